// Round 1
// baseline (692.231 us; speedup 1.0000x reference)
//
#include <hip/hip_runtime.h>
#include <stdint.h>

// ============================================================================
// Fused MHA w/ RoPE, MI355X bf16-MFMA implementation.
// Pipeline: f32->bf16 converts -> cos/sin table -> 3 proj GEMMs (fused RoPE /
// V-transpose epilogues) -> causal flash attention -> output GEMM (f32 out).
// Scratch: ws ~97MB; q_rope/k_rope live inside d_out (dead before final GEMM).
// ============================================================================

using u16 = unsigned short;
typedef __bf16 bf16_t;
typedef __bf16 bf16x8 __attribute__((ext_vector_type(8)));
typedef float  f32x4  __attribute__((ext_vector_type(4)));
typedef u16    u16x4  __attribute__((ext_vector_type(4)));

#define DEVI static __device__ __forceinline__
#define AS1 __attribute__((address_space(1)))
#define AS3 __attribute__((address_space(3)))
#define GLL16(g,l) __builtin_amdgcn_global_load_lds((const AS1 void*)(g), (AS3 void*)(l), 16, 0, 0)

DEVI u16 f2bf(float x){ bf16_t h=(bf16_t)x; return __builtin_bit_cast(u16,h); }
DEVI f32x4 mfma16(bf16x8 a, bf16x8 b, f32x4 c){
  return __builtin_amdgcn_mfma_f32_16x16x32_bf16(a,b,c,0,0,0);
}

// ---------------------------------------------------------------- converts
__global__ __launch_bounds__(256) void k_cvt(const float* __restrict__ in, u16* __restrict__ out){
  int i = blockIdx.x*256 + threadIdx.x;
  float4 v = ((const float4*)in)[i];
  u16x4 o = { f2bf(v.x), f2bf(v.y), f2bf(v.z), f2bf(v.w) };
  ((u16x4*)out)[i] = o;
}

// RoPE table: ct/st [S=2048][64] f32
__global__ __launch_bounds__(256) void k_tab(const int* __restrict__ pos, float* __restrict__ ct, float* __restrict__ stab){
  int i = blockIdx.x*256 + threadIdx.x;      // 0..131071
  int s = i>>6, f = i&63;
  float inv = __expf(-0.14391275442161033f * (float)f);  // 10000^(-f/64)
  float a = (float)pos[s] * inv;
  float sv, cv; sincosf(a, &sv, &cv);
  ct[i] = cv; stab[i] = sv;
}

// ---------------------------------------------------------------- GEMM
// C[M=8192][N=2048] = A[M][K=2048] * Bt[N][K]^T, bf16 in, 128x128 tile, BK=32.
// EPI: 0 = Q (RoPE + 1/sqrt(128) scale -> [bh][s][128] bf16)
//      1 = K (RoPE -> [bh][s][128] bf16)
//      2 = V (transpose -> [bh][128][s] bf16)
//      3 = O (f32 row-major out)
template<int EPI>
__global__ __launch_bounds__(256,2) void k_gemm(
    const bf16_t* __restrict__ A, const bf16_t* __restrict__ Bt,
    void* __restrict__ Out, const float* __restrict__ ct, const float* __restrict__ stab)
{
  __shared__ char lds[16384];                 // A tile [128][32]bf16 @0, B tile @8192
  const int tid = threadIdx.x, wave = tid>>6, lane = tid&63;
  const int rgrp = lane>>4, cidx = lane&15;
  const int mbase = blockIdx.y*128, nbase = blockIdx.x*128;
  const int wr = wave>>1, wc = wave&1;

  f32x4 acc[4][4] = {};

  const char* Ab = (const char*)A + (size_t)mbase*4096;
  const char* Bb = (const char*)Bt + (size_t)nbase*4096;
  const int sr0 = tid>>2;                     // staging row (issue 0), 0..63
  const int sc0 = (tid&3)*16;                 // staging col byte

  for (int kt=0; kt<64; ++kt){
    const int kb = kt*64;
    GLL16(Ab + (size_t)sr0*4096      + kb + sc0, lds +         wave*1024);
    GLL16(Ab + (size_t)(sr0+64)*4096 + kb + sc0, lds +  4096 + wave*1024);
    GLL16(Bb + (size_t)sr0*4096      + kb + sc0, lds +  8192 + wave*1024);
    GLL16(Bb + (size_t)(sr0+64)*4096 + kb + sc0, lds + 12288 + wave*1024);
    __syncthreads();
    bf16x8 af[4], bfr[4];
    #pragma unroll
    for (int i=0;i<4;++i) af[i]  = *(const bf16x8*)(lds +        (wr*64 + i*16 + cidx)*64 + rgrp*16);
    #pragma unroll
    for (int j=0;j<4;++j) bfr[j] = *(const bf16x8*)(lds + 8192 + (wc*64 + j*16 + cidx)*64 + rgrp*16);
    #pragma unroll
    for (int i=0;i<4;++i)
      #pragma unroll
      for (int j=0;j<4;++j)
        acc[i][j] = mfma16(af[i], bfr[j], acc[i][j]);
    __syncthreads();
  }

  if constexpr (EPI==3){
    float* O = (float*)Out;
    #pragma unroll
    for (int i=0;i<4;++i){
      const int m0 = mbase + wr*64 + i*16 + rgrp*4;
      #pragma unroll
      for (int j=0;j<4;++j){
        const int n = nbase + wc*64 + j*16 + cidx;
        #pragma unroll
        for (int r=0;r<4;++r)
          O[(size_t)(m0+r)*2048 + n] = acc[i][j][r];
      }
    }
  } else if constexpr (EPI==2){
    u16* O = (u16*)Out;                       // v_t [bh][128][2048]
    #pragma unroll
    for (int i=0;i<4;++i){
      const int m0 = mbase + wr*64 + i*16 + rgrp*4;
      const int b = m0>>11, s0 = m0&2047;
      #pragma unroll
      for (int j=0;j<4;++j){
        const int n = nbase + wc*64 + j*16 + cidx;
        const int h = n>>7, d = n&127;
        u16x4 pk = { f2bf(acc[i][j][0]), f2bf(acc[i][j][1]), f2bf(acc[i][j][2]), f2bf(acc[i][j][3]) };
        *(u16x4*)(O + ((size_t)((b*16+h)*128 + d)*2048 + s0)) = pk;
      }
    }
  } else {
    u16* O = (u16*)Out;                       // [bh][2048][128]
    #pragma unroll
    for (int j=0;j<4;++j){
      const int n = nbase + wc*64 + j*16 + cidx;
      const int h = n>>7, d = n&127, f = (n&127)>>1;
      #pragma unroll
      for (int i=0;i<4;++i){
        #pragma unroll
        for (int r=0;r<4;++r){
          const int m = mbase + wr*64 + i*16 + rgrp*4 + r;
          const int b = m>>11, s = m&2047;
          float v = acc[i][j][r];
          float p = __shfl_xor(v, 1, 64);     // RoPE partner: d^1 lives in lane^1
          float cv = ct[s*64+f], sv = stab[s*64+f];
          float o = (d&1) ? (p*sv + v*cv) : (v*cv - p*sv);
          if constexpr (EPI==0) o *= 0.08838834764831845f; // 1/sqrt(128)
          O[(size_t)(b*16+h)*262144 + (size_t)s*128 + d] = f2bf(o);
        }
      }
    }
  }
}

// ---------------------------------------------------------------- flash attn
// Grid (32 q-tiles, 64 bh). 4 waves; wave w owns q rows [qt*64+w*16, +16).
// K tile [64][128]bf16 + Vt tile [128][64]bf16 in LDS, XOR-swizzled
// (linear gload_lds dest + inverse-swizzled global source, rule 21).
__global__ __launch_bounds__(256,2) void k_attn(
  const bf16_t* __restrict__ Q, const bf16_t* __restrict__ K,
  const bf16_t* __restrict__ Vt, u16* __restrict__ Mg)
{
  __shared__ char kl[16384];
  __shared__ char vl[16384];
  __shared__ char pl[4*2304];                 // per-wave P 16 x 72 bf16 (144B rows)
  const int tid=threadIdx.x, wave=tid>>6, lane=tid&63;
  const int rgrp=lane>>4, cidx=lane&15;
  const int qt=blockIdx.x, bh=blockIdx.y;
  const int qbase=qt*64;

  bf16x8 qf[4];
  {
    const bf16_t* qp = Q + ((size_t)bh*2048 + qbase + wave*16 + cidx)*128 + rgrp*8;
    #pragma unroll
    for (int d=0; d<4; ++d) qf[d] = *(const bf16x8*)(qp + d*32);
  }
  f32x4 oacc[8] = {};
  float mrow[4] = {-1e30f,-1e30f,-1e30f,-1e30f};
  float lrow[4] = {0.f,0.f,0.f,0.f};

  const char* Kg = (const char*)K  + (size_t)bh*524288;
  const char* Vg = (const char*)Vt + (size_t)bh*524288;
  char* pw = pl + wave*2304;

  for (int kt=0; kt<=qt; ++kt){
    const int L0 = tid*16;
    #pragma unroll
    for (int i=0;i<4;++i){                    // K: LDS [64][128]bf16
      int L = i*4096 + L0;
      int row = L>>8;
      int inner = (L&255) ^ ((row&7)<<4);
      GLL16(Kg + (size_t)(kt*64+row)*256 + inner, kl + i*4096 + wave*1024);
    }
    #pragma unroll
    for (int i=0;i<4;++i){                    // Vt: LDS [128][64]bf16
      int L = i*4096 + L0;
      int d = L>>7;
      int inner = (L&127) ^ ((d&7)<<4);
      GLL16(Vg + (size_t)d*4096 + kt*128 + inner, vl + i*4096 + wave*1024);
    }
    __syncthreads();

    // S = Q K^T (Q pre-scaled)
    f32x4 stt[4];
    #pragma unroll
    for (int t=0;t<4;++t){
      f32x4 z = {0.f,0.f,0.f,0.f};
      const int key = t*16 + cidx;
      #pragma unroll
      for (int ds=0; ds<4; ++ds){
        const int off = (key*256 + ds*64 + rgrp*16) ^ ((key&7)<<4);
        bf16x8 kf = *(const bf16x8*)(kl + off);
        z = mfma16(qf[ds], kf, z);
      }
      stt[t] = z;
    }

    if (kt==qt){                              // diagonal tile: causal mask
      #pragma unroll
      for (int t=0;t<4;++t){
        const int key = qbase + t*16 + cidx;
        #pragma unroll
        for (int r=0;r<4;++r){
          const int row = qbase + wave*16 + rgrp*4 + r;
          if (key > row) stt[t][r] = -1e30f;
        }
      }
    }

    // online softmax (row r of fragment lives in the 16-lane group rgrp)
    float corr[4];
    #pragma unroll
    for (int r=0;r<4;++r){
      float v = fmaxf(fmaxf(stt[0][r],stt[1][r]), fmaxf(stt[2][r],stt[3][r]));
      #pragma unroll
      for (int m_=1;m_<16;m_<<=1) v = fmaxf(v, __shfl_xor(v, m_, 64));
      float mn = fmaxf(mrow[r], v);
      corr[r] = __expf(mrow[r]-mn);
      mrow[r] = mn;
    }
    float lt[4]={0.f,0.f,0.f,0.f};
    #pragma unroll
    for (int t=0;t<4;++t)
      #pragma unroll
      for (int r=0;r<4;++r){
        float p = __expf(stt[t][r]-mrow[r]);
        stt[t][r]=p; lt[r]+=p;
      }
    #pragma unroll
    for (int r=0;r<4;++r){
      float v = lt[r];
      #pragma unroll
      for (int m_=1;m_<16;m_<<=1) v += __shfl_xor(v, m_, 64);
      lrow[r] = lrow[r]*corr[r] + v;
    }
    #pragma unroll
    for (int dsub=0;dsub<8;++dsub)
      #pragma unroll
      for (int r=0;r<4;++r) oacc[dsub][r]*=corr[r];

    // P (C-layout) -> LDS -> A-fragment layout
    #pragma unroll
    for (int t=0;t<4;++t)
      #pragma unroll
      for (int r=0;r<4;++r)
        *(u16*)(pw + (rgrp*4+r)*144 + (t*16+cidx)*2) = f2bf(stt[t][r]);
    asm volatile("s_waitcnt lgkmcnt(0)" ::: "memory");

    #pragma unroll
    for (int ks=0; ks<2; ++ks){
      bf16x8 pa = *(const bf16x8*)(pw + cidx*144 + ks*64 + rgrp*16);
      #pragma unroll
      for (int dsub=0; dsub<8; ++dsub){
        const int d = dsub*16 + cidx;
        const int off = (d*128 + ks*64 + rgrp*16) ^ ((d&7)<<4);
        bf16x8 vf = *(const bf16x8*)(vl + off);
        oacc[dsub] = mfma16(pa, vf, oacc[dsub]);
      }
    }
    __syncthreads();
  }

  const int b = bh>>4, h = bh&15;
  float inv[4];
  #pragma unroll
  for (int r=0;r<4;++r) inv[r] = 1.f/lrow[r];
  #pragma unroll
  for (int dsub=0;dsub<8;++dsub){
    const int col = h*128 + dsub*16 + cidx;
    #pragma unroll
    for (int r=0;r<4;++r){
      const int srow = qbase + wave*16 + rgrp*4 + r;
      Mg[((size_t)b*2048 + srow)*2048 + col] = f2bf(oacc[dsub][r]*inv[r]);
    }
  }
}

// ---------------------------------------------------------------- launch
extern "C" void kernel_launch(void* const* d_in, const int* in_sizes, int n_in,
                              void* d_out, int out_size, void* d_ws, size_t ws_size,
                              hipStream_t stream)
{
  (void)in_sizes; (void)n_in; (void)out_size; (void)ws_size;
  const float* x  = (const float*)d_in[0];
  const int*   tp = (const int*)d_in[1];
  const float* Wq = (const float*)d_in[2];
  const float* Wk = (const float*)d_in[3];
  const float* Wv = (const float*)d_in[4];
  const float* Wo = (const float*)d_in[5];

  char* ws = (char*)d_ws;
  bf16_t* xb  = (bf16_t*)(ws);                 // 33.5MB, reused as merged later
  bf16_t* wqb = (bf16_t*)(ws + 33554432);
  bf16_t* wkb = (bf16_t*)(ws + 41943040);
  bf16_t* wvb = (bf16_t*)(ws + 50331648);
  bf16_t* wob = (bf16_t*)(ws + 58720256);
  bf16_t* vt  = (bf16_t*)(ws + 67108864);      // 33.5MB
  float*  ct  = (float*) (ws + 100663296);     // 512KB
  float*  stb = (float*) (ws + 101187584);     // 512KB  (end ~97MB)
  bf16_t* qr  = (bf16_t*)d_out;                // q_rope in d_out (dead before final GEMM)
  bf16_t* kr  = (bf16_t*)((char*)d_out + 33554432);
  bf16_t* mg  = xb;                            // merged reuses xb

  k_cvt<<<16384,256,0,stream>>>(x,  (u16*)xb);
  k_cvt<<< 4096,256,0,stream>>>(Wq, (u16*)wqb);
  k_cvt<<< 4096,256,0,stream>>>(Wk, (u16*)wkb);
  k_cvt<<< 4096,256,0,stream>>>(Wv, (u16*)wvb);
  k_cvt<<< 4096,256,0,stream>>>(Wo, (u16*)wob);
  k_tab<<<  512,256,0,stream>>>(tp, ct, stb);

  dim3 gg(16,64);
  k_gemm<0><<<gg,256,0,stream>>>(xb, wqb, qr, ct, stb);
  k_gemm<1><<<gg,256,0,stream>>>(xb, wkb, kr, ct, stb);
  k_gemm<2><<<gg,256,0,stream>>>(xb, wvb, vt, nullptr, nullptr);
  k_attn<<<dim3(32,64),256,0,stream>>>(qr, kr, vt, (u16*)mg);
  k_gemm<3><<<gg,256,0,stream>>>(mg, wob, d_out, nullptr, nullptr);
}

// Round 2
// 586.830 us; speedup vs baseline: 1.1796x; 1.1796x over previous
//
#include <hip/hip_runtime.h>
#include <stdint.h>

// ============================================================================
// Fused MHA w/ RoPE, MI355X bf16-MFMA implementation.
// Pipeline: f32->bf16 converts -> cos/sin table -> 3 proj GEMMs (fused RoPE /
// V-transpose epilogues) -> causal flash attention -> output GEMM (f32 out).
// R1: attn rewritten: QBLK=128 (2 M-frags/wave), double-buffered K/V with
// counted vmcnt + raw s_barrier, LPT (heavy-first) block order, setprio,
// defer-max, swizzled unpadded P. GEMMs unchanged.
// ============================================================================

using u16 = unsigned short;
typedef __bf16 bf16_t;
typedef __bf16 bf16x8 __attribute__((ext_vector_type(8)));
typedef float  f32x4  __attribute__((ext_vector_type(4)));
typedef u16    u16x4  __attribute__((ext_vector_type(4)));

#define DEVI static __device__ __forceinline__
#define AS1 __attribute__((address_space(1)))
#define AS3 __attribute__((address_space(3)))
#define GLL16(g,l) __builtin_amdgcn_global_load_lds((const AS1 void*)(g), (AS3 void*)(l), 16, 0, 0)

DEVI u16 f2bf(float x){ bf16_t h=(bf16_t)x; return __builtin_bit_cast(u16,h); }
DEVI f32x4 mfma16(bf16x8 a, bf16x8 b, f32x4 c){
  return __builtin_amdgcn_mfma_f32_16x16x32_bf16(a,b,c,0,0,0);
}

// ---------------------------------------------------------------- converts
__global__ __launch_bounds__(256) void k_cvt(const float* __restrict__ in, u16* __restrict__ out){
  int i = blockIdx.x*256 + threadIdx.x;
  float4 v = ((const float4*)in)[i];
  u16x4 o = { f2bf(v.x), f2bf(v.y), f2bf(v.z), f2bf(v.w) };
  ((u16x4*)out)[i] = o;
}

// RoPE table: ct/st [S=2048][64] f32
__global__ __launch_bounds__(256) void k_tab(const int* __restrict__ pos, float* __restrict__ ct, float* __restrict__ stab){
  int i = blockIdx.x*256 + threadIdx.x;      // 0..131071
  int s = i>>6, f = i&63;
  float inv = __expf(-0.14391275442161033f * (float)f);  // 10000^(-f/64)
  float a = (float)pos[s] * inv;
  float sv, cv; sincosf(a, &sv, &cv);
  ct[i] = cv; stab[i] = sv;
}

// ---------------------------------------------------------------- GEMM
// C[M=8192][N=2048] = A[M][K=2048] * Bt[N][K]^T, bf16 in, 128x128 tile, BK=32.
// EPI: 0 = Q (RoPE + 1/sqrt(128) scale -> [bh][s][128] bf16)
//      1 = K (RoPE -> [bh][s][128] bf16)
//      2 = V (transpose -> [bh][128][s] bf16)
//      3 = O (f32 row-major out)
template<int EPI>
__global__ __launch_bounds__(256,2) void k_gemm(
    const bf16_t* __restrict__ A, const bf16_t* __restrict__ Bt,
    void* __restrict__ Out, const float* __restrict__ ct, const float* __restrict__ stab)
{
  __shared__ char lds[16384];                 // A tile [128][32]bf16 @0, B tile @8192
  const int tid = threadIdx.x, wave = tid>>6, lane = tid&63;
  const int rgrp = lane>>4, cidx = lane&15;
  const int mbase = blockIdx.y*128, nbase = blockIdx.x*128;
  const int wr = wave>>1, wc = wave&1;

  f32x4 acc[4][4] = {};

  const char* Ab = (const char*)A + (size_t)mbase*4096;
  const char* Bb = (const char*)Bt + (size_t)nbase*4096;
  const int sr0 = tid>>2;                     // staging row (issue 0), 0..63
  const int sc0 = (tid&3)*16;                 // staging col byte

  for (int kt=0; kt<64; ++kt){
    const int kb = kt*64;
    GLL16(Ab + (size_t)sr0*4096      + kb + sc0, lds +         wave*1024);
    GLL16(Ab + (size_t)(sr0+64)*4096 + kb + sc0, lds +  4096 + wave*1024);
    GLL16(Bb + (size_t)sr0*4096      + kb + sc0, lds +  8192 + wave*1024);
    GLL16(Bb + (size_t)(sr0+64)*4096 + kb + sc0, lds + 12288 + wave*1024);
    __syncthreads();
    bf16x8 af[4], bfr[4];
    #pragma unroll
    for (int i=0;i<4;++i) af[i]  = *(const bf16x8*)(lds +        (wr*64 + i*16 + cidx)*64 + rgrp*16);
    #pragma unroll
    for (int j=0;j<4;++j) bfr[j] = *(const bf16x8*)(lds + 8192 + (wc*64 + j*16 + cidx)*64 + rgrp*16);
    #pragma unroll
    for (int i=0;i<4;++i)
      #pragma unroll
      for (int j=0;j<4;++j)
        acc[i][j] = mfma16(af[i], bfr[j], acc[i][j]);
    __syncthreads();
  }

  if constexpr (EPI==3){
    float* O = (float*)Out;
    #pragma unroll
    for (int i=0;i<4;++i){
      const int m0 = mbase + wr*64 + i*16 + rgrp*4;
      #pragma unroll
      for (int j=0;j<4;++j){
        const int n = nbase + wc*64 + j*16 + cidx;
        #pragma unroll
        for (int r=0;r<4;++r)
          O[(size_t)(m0+r)*2048 + n] = acc[i][j][r];
      }
    }
  } else if constexpr (EPI==2){
    u16* O = (u16*)Out;                       // v_t [bh][128][2048]
    #pragma unroll
    for (int i=0;i<4;++i){
      const int m0 = mbase + wr*64 + i*16 + rgrp*4;
      const int b = m0>>11, s0 = m0&2047;
      #pragma unroll
      for (int j=0;j<4;++j){
        const int n = nbase + wc*64 + j*16 + cidx;
        const int h = n>>7, d = n&127;
        u16x4 pk = { f2bf(acc[i][j][0]), f2bf(acc[i][j][1]), f2bf(acc[i][j][2]), f2bf(acc[i][j][3]) };
        *(u16x4*)(O + ((size_t)((b*16+h)*128 + d)*2048 + s0)) = pk;
      }
    }
  } else {
    u16* O = (u16*)Out;                       // [bh][2048][128]
    #pragma unroll
    for (int j=0;j<4;++j){
      const int n = nbase + wc*64 + j*16 + cidx;
      const int h = n>>7, d = n&127, f = (n&127)>>1;
      #pragma unroll
      for (int i=0;i<4;++i){
        #pragma unroll
        for (int r=0;r<4;++r){
          const int m = mbase + wr*64 + i*16 + rgrp*4 + r;
          const int b = m>>11, s = m&2047;
          float v = acc[i][j][r];
          float p = __shfl_xor(v, 1, 64);     // RoPE partner: d^1 lives in lane^1
          float cv = ct[s*64+f], sv = stab[s*64+f];
          float o = (d&1) ? (p*sv + v*cv) : (v*cv - p*sv);
          if constexpr (EPI==0) o *= 0.08838834764831845f; // 1/sqrt(128)
          O[(size_t)(b*16+h)*262144 + (size_t)s*128 + d] = f2bf(o);
        }
      }
    }
  }
}

// ---------------------------------------------------------------- flash attn
// 1-D grid, 1024 blocks, LPT order: qt = 15 - bid/64 (heavy first), bh = bid%64.
// QBLK=128: wave w owns q rows [qt*128 + w*32, +32) = 2 M-fragments.
// K tile [64][128] + Vt tile [128][64] double-buffered in LDS (XOR-swizzled,
// rule 21: linear gload_lds dest + inverse-swizzled global source + swz read).
// Counted vmcnt(8) + raw s_barrier keeps next tile's 8 GLLs in flight across
// the barrier (T3/T4). setprio around MFMA clusters (T5). Defer-max (T13).
__global__ __launch_bounds__(256,2) void k_attn(
  const bf16_t* __restrict__ Q, const bf16_t* __restrict__ K,
  const bf16_t* __restrict__ Vt, u16* __restrict__ Mg)
{
  __shared__ char kl[2][16384];
  __shared__ char vl[2][16384];
  __shared__ char pl[4][4096];                // per-wave P: 32 rows x 128B, XOR-swz
  const int tid=threadIdx.x, wave=tid>>6, lane=tid&63;
  const int rgrp=lane>>4, cidx=lane&15;
  const int bid=blockIdx.x;
  const int qt = 15 - (bid>>6);
  const int bh = bid & 63;
  const int qbase = qt*128;
  const int last = 2*qt + 1;                  // inclusive last k-tile

  bf16x8 qf[2][4];
  #pragma unroll
  for (int m=0;m<2;++m){
    const bf16_t* qp = Q + ((size_t)bh*2048 + qbase + wave*32 + m*16 + cidx)*128 + rgrp*8;
    #pragma unroll
    for (int ds=0; ds<4; ++ds) qf[m][ds] = *(const bf16x8*)(qp + ds*32);
  }
  f32x4 oacc[2][8] = {};
  float mrow[2][4], lrow[2][4];
  #pragma unroll
  for (int m=0;m<2;++m)
    #pragma unroll
    for (int r=0;r<4;++r){ mrow[m][r]=-1e30f; lrow[m][r]=0.f; }

  const char* Kg = (const char*)K  + (size_t)bh*524288;
  const char* Vg = (const char*)Vt + (size_t)bh*524288;
  char* pw = pl[wave];
  const int L0 = tid*16;

  #define STAGE(buf, kt_) do{                                                  \
    _Pragma("unroll")                                                          \
    for (int i_=0;i_<4;++i_){                                                  \
      int L_ = i_*4096 + L0;                                                   \
      int row_ = L_>>8;                                                        \
      int in_ = (L_&255) ^ ((row_&7)<<4);                                      \
      GLL16(Kg + (size_t)((kt_)*64+row_)*256 + in_, &kl[buf][i_*4096 + wave*1024]); \
    }                                                                          \
    _Pragma("unroll")                                                          \
    for (int i_=0;i_<4;++i_){                                                  \
      int L_ = i_*4096 + L0;                                                   \
      int d_ = L_>>7;                                                          \
      int in_ = (L_&127) ^ ((d_&7)<<4);                                        \
      GLL16(Vg + (size_t)d_*4096 + (kt_)*128 + in_, &vl[buf][i_*4096 + wave*1024]); \
    }                                                                          \
  }while(0)

  STAGE(0, 0);
  int cur = 0;
  for (int kt=0; kt<=last; ++kt){
    const bool pf = (kt < last);
    if (pf) STAGE(cur^1, kt+1);               // 8 more GLLs in flight
    if (pf) asm volatile("s_waitcnt vmcnt(8)" ::: "memory");
    else    asm volatile("s_waitcnt vmcnt(0)" ::: "memory");
    __builtin_amdgcn_s_barrier();             // buf[cur] ready everywhere

    // ---- S = Q K^T (Q pre-scaled by 1/sqrt(128))
    f32x4 stt[2][4];
    #pragma unroll
    for (int m=0;m<2;++m)
      #pragma unroll
      for (int t=0;t<4;++t) stt[m][t] = (f32x4){0.f,0.f,0.f,0.f};
    __builtin_amdgcn_s_setprio(1);
    #pragma unroll
    for (int t=0;t<4;++t){
      const int key = t*16 + cidx;
      #pragma unroll
      for (int ds=0; ds<4; ++ds){
        const int off = (key*256 + ds*64 + rgrp*16) ^ ((key&7)<<4);
        bf16x8 kf = *(const bf16x8*)(&kl[cur][off]);
        stt[0][t] = mfma16(qf[0][ds], kf, stt[0][t]);
        stt[1][t] = mfma16(qf[1][ds], kf, stt[1][t]);
      }
    }
    __builtin_amdgcn_s_setprio(0);

    // ---- causal mask (only possible on the last two tiles of this q-block)
    if (kt >= 2*qt){
      #pragma unroll
      for (int m=0;m<2;++m)
        #pragma unroll
        for (int t=0;t<4;++t){
          const int gkey = kt*64 + t*16 + cidx;
          #pragma unroll
          for (int r=0;r<4;++r){
            const int grow = qbase + wave*32 + m*16 + rgrp*4 + r;
            if (gkey > grow) stt[m][t][r] = -1e30f;
          }
        }
    }

    // ---- online softmax (row r of frag m lives in 16-lane group rgrp)
    #pragma unroll
    for (int m=0;m<2;++m){
      float vmax[4];
      #pragma unroll
      for (int r=0;r<4;++r){
        float v = fmaxf(fmaxf(stt[m][0][r],stt[m][1][r]), fmaxf(stt[m][2][r],stt[m][3][r]));
        #pragma unroll
        for (int s_=1;s_<16;s_<<=1) v = fmaxf(v, __shfl_xor(v, s_, 64));
        vmax[r] = v;
      }
      bool small = true;
      #pragma unroll
      for (int r=0;r<4;++r) small = small && (vmax[r] <= mrow[m][r] + 8.f);
      if (!__all(small)){                     // T13: rescale only on real growth
        #pragma unroll
        for (int r=0;r<4;++r){
          float mn = fmaxf(mrow[m][r], vmax[r]);
          float c = __expf(mrow[m][r]-mn);
          mrow[m][r]=mn; lrow[m][r]*=c;
          #pragma unroll
          for (int d=0;d<8;++d) oacc[m][d][r]*=c;
        }
      }
      float lt[4]={0.f,0.f,0.f,0.f};
      #pragma unroll
      for (int t=0;t<4;++t)
        #pragma unroll
        for (int r=0;r<4;++r){
          float p = __expf(stt[m][t][r]-mrow[m][r]);
          stt[m][t][r]=p; lt[r]+=p;
        }
      #pragma unroll
      for (int r=0;r<4;++r){
        float v = lt[r];
        #pragma unroll
        for (int s_=1;s_<16;s_<<=1) v += __shfl_xor(v, s_, 64);
        lrow[m][r] += v;
      }
    }

    // ---- P (C-layout) -> per-wave LDS (XOR-swz) -> A-fragment layout
    #pragma unroll
    for (int m=0;m<2;++m)
      #pragma unroll
      for (int t=0;t<4;++t)
        #pragma unroll
        for (int r=0;r<4;++r){
          const int row = m*16 + rgrp*4 + r;
          const int off = (row*128 + (t*16+cidx)*2) ^ ((row&7)<<4);
          *(u16*)(pw + off) = f2bf(stt[m][t][r]);
        }
    asm volatile("s_waitcnt lgkmcnt(0)" ::: "memory");
    __builtin_amdgcn_sched_barrier(0);

    __builtin_amdgcn_s_setprio(1);
    #pragma unroll
    for (int ks=0; ks<2; ++ks){
      bf16x8 pa0 = *(const bf16x8*)(pw + (((      cidx)*128 + ks*64 + rgrp*16) ^ ((cidx&7)<<4)));
      bf16x8 pa1 = *(const bf16x8*)(pw + (((16 +  cidx)*128 + ks*64 + rgrp*16) ^ ((cidx&7)<<4)));
      #pragma unroll
      for (int dsub=0; dsub<8; ++dsub){
        const int d = dsub*16 + cidx;
        const int off = (d*128 + ks*64 + rgrp*16) ^ ((d&7)<<4);
        bf16x8 vf = *(const bf16x8*)(&vl[cur][off]);
        oacc[0][dsub] = mfma16(pa0, vf, oacc[0][dsub]);
        oacc[1][dsub] = mfma16(pa1, vf, oacc[1][dsub]);
      }
    }
    __builtin_amdgcn_s_setprio(0);
    __builtin_amdgcn_s_barrier();             // all reads of buf[cur] done
    cur ^= 1;
  }
  #undef STAGE

  const int b = bh>>4, h = bh&15;
  #pragma unroll
  for (int m=0;m<2;++m){
    float inv[4];
    #pragma unroll
    for (int r=0;r<4;++r) inv[r] = 1.f/lrow[m][r];
    #pragma unroll
    for (int dsub=0;dsub<8;++dsub){
      const int col = h*128 + dsub*16 + cidx;
      #pragma unroll
      for (int r=0;r<4;++r){
        const int srow = qbase + wave*32 + m*16 + rgrp*4 + r;
        Mg[((size_t)b*2048 + srow)*2048 + col] = f2bf(oacc[m][dsub][r]*inv[r]);
      }
    }
  }
}

// ---------------------------------------------------------------- launch
extern "C" void kernel_launch(void* const* d_in, const int* in_sizes, int n_in,
                              void* d_out, int out_size, void* d_ws, size_t ws_size,
                              hipStream_t stream)
{
  (void)in_sizes; (void)n_in; (void)out_size; (void)ws_size;
  const float* x  = (const float*)d_in[0];
  const int*   tp = (const int*)d_in[1];
  const float* Wq = (const float*)d_in[2];
  const float* Wk = (const float*)d_in[3];
  const float* Wv = (const float*)d_in[4];
  const float* Wo = (const float*)d_in[5];

  char* ws = (char*)d_ws;
  bf16_t* xb  = (bf16_t*)(ws);                 // 33.5MB, reused as merged later
  bf16_t* wqb = (bf16_t*)(ws + 33554432);
  bf16_t* wkb = (bf16_t*)(ws + 41943040);
  bf16_t* wvb = (bf16_t*)(ws + 50331648);
  bf16_t* wob = (bf16_t*)(ws + 58720256);
  bf16_t* vt  = (bf16_t*)(ws + 67108864);      // 33.5MB
  float*  ct  = (float*) (ws + 100663296);     // 512KB
  float*  stb = (float*) (ws + 101187584);     // 512KB  (end ~97MB)
  bf16_t* qr  = (bf16_t*)d_out;                // q_rope in d_out (dead before final GEMM)
  bf16_t* kr  = (bf16_t*)((char*)d_out + 33554432);
  bf16_t* mg  = xb;                            // merged reuses xb

  k_cvt<<<16384,256,0,stream>>>(x,  (u16*)xb);
  k_cvt<<< 4096,256,0,stream>>>(Wq, (u16*)wqb);
  k_cvt<<< 4096,256,0,stream>>>(Wk, (u16*)wkb);
  k_cvt<<< 4096,256,0,stream>>>(Wv, (u16*)wvb);
  k_cvt<<< 4096,256,0,stream>>>(Wo, (u16*)wob);
  k_tab<<<  512,256,0,stream>>>(tp, ct, stb);

  dim3 gg(16,64);
  k_gemm<0><<<gg,256,0,stream>>>(xb, wqb, qr, ct, stb);
  k_gemm<1><<<gg,256,0,stream>>>(xb, wkb, kr, ct, stb);
  k_gemm<2><<<gg,256,0,stream>>>(xb, wvb, vt, nullptr, nullptr);
  k_attn<<<1024,256,0,stream>>>(qr, kr, vt, (u16*)mg);
  k_gemm<3><<<gg,256,0,stream>>>(mg, wob, d_out, nullptr, nullptr);
}

// Round 3
// 487.522 us; speedup vs baseline: 1.4199x; 1.2037x over previous
//
#include <hip/hip_runtime.h>
#include <stdint.h>

// ============================================================================
// Fused MHA w/ RoPE, MI355X bf16-MFMA implementation.
// R2: attn uses swapped QK^T (S[key][q]) so softmax is in-lane (15 fmax + 2
// shfl vs 64 bpermutes), packed ds_write_b64 P-stores; QKV projections fused
// into one N=6144 GEMM. Double-buffered K/V + counted vmcnt + LPT retained.
// ============================================================================

using u16 = unsigned short;
typedef __bf16 bf16_t;
typedef __bf16 bf16x8 __attribute__((ext_vector_type(8)));
typedef float  f32x4  __attribute__((ext_vector_type(4)));
typedef u16    u16x4  __attribute__((ext_vector_type(4)));

#define DEVI static __device__ __forceinline__
#define AS1 __attribute__((address_space(1)))
#define AS3 __attribute__((address_space(3)))
#define GLL16(g,l) __builtin_amdgcn_global_load_lds((const AS1 void*)(g), (AS3 void*)(l), 16, 0, 0)

DEVI u16 f2bf(float x){ bf16_t h=(bf16_t)x; return __builtin_bit_cast(u16,h); }
DEVI f32x4 mfma16(bf16x8 a, bf16x8 b, f32x4 c){
  return __builtin_amdgcn_mfma_f32_16x16x32_bf16(a,b,c,0,0,0);
}

// ---------------------------------------------------------------- converts
__global__ __launch_bounds__(256) void k_cvt(const float* __restrict__ in, u16* __restrict__ out){
  int i = blockIdx.x*256 + threadIdx.x;
  float4 v = ((const float4*)in)[i];
  u16x4 o = { f2bf(v.x), f2bf(v.y), f2bf(v.z), f2bf(v.w) };
  ((u16x4*)out)[i] = o;
}

// RoPE table: ct/st [S=2048][64] f32
__global__ __launch_bounds__(256) void k_tab(const int* __restrict__ pos, float* __restrict__ ct, float* __restrict__ stab){
  int i = blockIdx.x*256 + threadIdx.x;      // 0..131071
  int s = i>>6, f = i&63;
  float inv = __expf(-0.14391275442161033f * (float)f);  // 10000^(-f/64)
  float a = (float)pos[s] * inv;
  float sv, cv; sincosf(a, &sv, &cv);
  ct[i] = cv; stab[i] = sv;
}

// ---------------------------------------------------------------- GEMM
// C[M=8192][N] = A[M][K=2048] * Bt[N][K]^T, bf16 in, 128x128 tile, BK=32.
// EPI==4: N=6144 fused QKV — seg 0: RoPE+scale->O0 (q [bh][s][128]),
//         seg 1: RoPE->O1 (k), seg 2: transpose->O2 (v_t [bh][128][s]).
// EPI==3: N=2048, f32 row-major to O0.
template<int EPI>
__global__ __launch_bounds__(256,2) void k_gemm(
    const bf16_t* __restrict__ A, const bf16_t* __restrict__ Bt,
    void* __restrict__ O0, void* __restrict__ O1, void* __restrict__ O2,
    const float* __restrict__ ct, const float* __restrict__ stab)
{
  __shared__ char lds[16384];                 // A tile [128][32]bf16 @0, B tile @8192
  const int tid = threadIdx.x, wave = tid>>6, lane = tid&63;
  const int rgrp = lane>>4, cidx = lane&15;
  const int mbase = blockIdx.y*128, nbase = blockIdx.x*128;
  const int wr = wave>>1, wc = wave&1;

  f32x4 acc[4][4] = {};

  const char* Ab = (const char*)A + (size_t)mbase*4096;
  const char* Bb = (const char*)Bt + (size_t)nbase*4096;
  const int sr0 = tid>>2;                     // staging row (issue 0), 0..63
  const int sc0 = (tid&3)*16;                 // staging col byte

  for (int kt=0; kt<64; ++kt){
    const int kb = kt*64;
    GLL16(Ab + (size_t)sr0*4096      + kb + sc0, lds +         wave*1024);
    GLL16(Ab + (size_t)(sr0+64)*4096 + kb + sc0, lds +  4096 + wave*1024);
    GLL16(Bb + (size_t)sr0*4096      + kb + sc0, lds +  8192 + wave*1024);
    GLL16(Bb + (size_t)(sr0+64)*4096 + kb + sc0, lds + 12288 + wave*1024);
    __syncthreads();
    bf16x8 af[4], bfr[4];
    #pragma unroll
    for (int i=0;i<4;++i) af[i]  = *(const bf16x8*)(lds +        (wr*64 + i*16 + cidx)*64 + rgrp*16);
    #pragma unroll
    for (int j=0;j<4;++j) bfr[j] = *(const bf16x8*)(lds + 8192 + (wc*64 + j*16 + cidx)*64 + rgrp*16);
    #pragma unroll
    for (int i=0;i<4;++i)
      #pragma unroll
      for (int j=0;j<4;++j)
        acc[i][j] = mfma16(af[i], bfr[j], acc[i][j]);
    __syncthreads();
  }

  if constexpr (EPI==3){
    float* O = (float*)O0;
    #pragma unroll
    for (int i=0;i<4;++i){
      const int m0 = mbase + wr*64 + i*16 + rgrp*4;
      #pragma unroll
      for (int j=0;j<4;++j){
        const int n = nbase + wc*64 + j*16 + cidx;
        #pragma unroll
        for (int r=0;r<4;++r)
          O[(size_t)(m0+r)*2048 + n] = acc[i][j][r];
      }
    }
  } else {
    const int seg = nbase>>11;                // block-uniform: 0=Q, 1=K, 2=V
    if (seg==2){
      u16* O = (u16*)O2;                      // v_t [bh][128][2048]
      #pragma unroll
      for (int i=0;i<4;++i){
        const int m0 = mbase + wr*64 + i*16 + rgrp*4;
        const int b = m0>>11, s0 = m0&2047;
        #pragma unroll
        for (int j=0;j<4;++j){
          const int nl = (nbase + wc*64 + j*16 + cidx) & 2047;
          const int h = nl>>7, d = nl&127;
          u16x4 pk = { f2bf(acc[i][j][0]), f2bf(acc[i][j][1]), f2bf(acc[i][j][2]), f2bf(acc[i][j][3]) };
          *(u16x4*)(O + ((size_t)((b*16+h)*128 + d)*2048 + s0)) = pk;
        }
      }
    } else {
      u16* O = seg ? (u16*)O1 : (u16*)O0;     // [bh][2048][128]
      const float qs = seg ? 1.0f : 0.08838834764831845f;  // 1/sqrt(128) on Q
      #pragma unroll
      for (int j=0;j<4;++j){
        const int nl = (nbase + wc*64 + j*16 + cidx) & 2047;
        const int h = nl>>7, d = nl&127, f = (nl&127)>>1;
        #pragma unroll
        for (int i=0;i<4;++i){
          #pragma unroll
          for (int r=0;r<4;++r){
            const int m = mbase + wr*64 + i*16 + rgrp*4 + r;
            const int b = m>>11, s = m&2047;
            float v = acc[i][j][r];
            float p = __shfl_xor(v, 1, 64);   // RoPE partner: d^1 lives in lane^1
            float cv = ct[s*64+f], sv = stab[s*64+f];
            float o = (d&1) ? (p*sv + v*cv) : (v*cv - p*sv);
            o *= qs;
            O[(size_t)(b*16+h)*262144 + (size_t)s*128 + d] = f2bf(o);
          }
        }
      }
    }
  }
}

// ---------------------------------------------------------------- flash attn
// 1-D grid, 1024 blocks, LPT order: qt = 15 - bid/64, bh = bid%64.
// QBLK=128: wave w owns q rows [qt*128 + w*32, +32) = 2 M-fragments.
// Swapped QK^T: stt[m][t] = mfma(K_frag, Q_frag) -> S[key][q], q = lane&15.
// Softmax: in-lane 16-value reduce + shfl_xor(16,32). P packed as u16x4 ->
// 8 ds_write_b64/wave. K/V double-buffered, XOR-swizzled (rule 21), counted
// vmcnt(8) + raw s_barrier (T3/T4), setprio (T5), defer-max (T13).
__global__ __launch_bounds__(256,2) void k_attn(
  const bf16_t* __restrict__ Q, const bf16_t* __restrict__ K,
  const bf16_t* __restrict__ Vt, u16* __restrict__ Mg)
{
  __shared__ char kl[2][16384];
  __shared__ char vl[2][16384];
  __shared__ char pl[4][4096];                // per-wave P: 32 q-rows x 128B, XOR-swz
  const int tid=threadIdx.x, wave=tid>>6, lane=tid&63;
  const int rgrp=lane>>4, cidx=lane&15;
  const int bid=blockIdx.x;
  const int qt = 15 - (bid>>6);
  const int bh = bid & 63;
  const int qbase = qt*128;
  const int last = 2*qt + 1;                  // inclusive last k-tile

  bf16x8 qf[2][4];                            // B-operand: lane <- q row m*16+cidx
  #pragma unroll
  for (int m=0;m<2;++m){
    const bf16_t* qp = Q + ((size_t)bh*2048 + qbase + wave*32 + m*16 + cidx)*128 + rgrp*8;
    #pragma unroll
    for (int ds=0; ds<4; ++ds) qf[m][ds] = *(const bf16x8*)(qp + ds*32);
  }
  f32x4 oacc[2][8] = {};
  float mrow[2] = {-1e30f,-1e30f};
  float lrow[2] = {0.f,0.f};

  const char* Kg = (const char*)K  + (size_t)bh*524288;
  const char* Vg = (const char*)Vt + (size_t)bh*524288;
  char* pw = pl[wave];
  const int L0 = tid*16;
  const int qrow0 = qbase + wave*32 + cidx;   // q-row of frag m: qrow0 + m*16

  #define STAGE(buf, kt_) do{                                                  \
    _Pragma("unroll")                                                          \
    for (int i_=0;i_<4;++i_){                                                  \
      int L_ = i_*4096 + L0;                                                   \
      int row_ = L_>>8;                                                        \
      int in_ = (L_&255) ^ ((row_&7)<<4);                                      \
      GLL16(Kg + (size_t)((kt_)*64+row_)*256 + in_, &kl[buf][i_*4096 + wave*1024]); \
    }                                                                          \
    _Pragma("unroll")                                                          \
    for (int i_=0;i_<4;++i_){                                                  \
      int L_ = i_*4096 + L0;                                                   \
      int d_ = L_>>7;                                                          \
      int in_ = (L_&127) ^ ((d_&7)<<4);                                        \
      GLL16(Vg + (size_t)d_*4096 + (kt_)*128 + in_, &vl[buf][i_*4096 + wave*1024]); \
    }                                                                          \
  }while(0)

  STAGE(0, 0);
  int cur = 0;
  for (int kt=0; kt<=last; ++kt){
    const bool pf = (kt < last);
    if (pf) STAGE(cur^1, kt+1);               // 8 more GLLs in flight
    if (pf) asm volatile("s_waitcnt vmcnt(8)" ::: "memory");
    else    asm volatile("s_waitcnt vmcnt(0)" ::: "memory");
    __builtin_amdgcn_s_barrier();             // buf[cur] ready everywhere

    // ---- S^T = K Q^T : stt[m][t][r] = S[key = kt*64+t*16+rgrp*4+r][q = qrow0+m*16]
    f32x4 stt[2][4];
    #pragma unroll
    for (int m=0;m<2;++m)
      #pragma unroll
      for (int t=0;t<4;++t) stt[m][t] = (f32x4){0.f,0.f,0.f,0.f};
    __builtin_amdgcn_s_setprio(1);
    #pragma unroll
    for (int t=0;t<4;++t){
      const int krow = t*16 + cidx;           // A-operand: lane <- K row krow
      #pragma unroll
      for (int ds=0; ds<4; ++ds){
        const int off = (krow*256 + ds*64 + rgrp*16) ^ ((krow&7)<<4);
        bf16x8 kf = *(const bf16x8*)(&kl[cur][off]);
        stt[0][t] = mfma16(kf, qf[0][ds], stt[0][t]);
        stt[1][t] = mfma16(kf, qf[1][ds], stt[1][t]);
      }
    }
    __builtin_amdgcn_s_setprio(0);

    // ---- causal mask (only the last two tiles of this q-block can clip)
    if (kt >= 2*qt){
      #pragma unroll
      for (int m=0;m<2;++m){
        const int q = qrow0 + m*16;
        #pragma unroll
        for (int t=0;t<4;++t){
          #pragma unroll
          for (int r=0;r<4;++r){
            const int key = kt*64 + t*16 + rgrp*4 + r;
            if (key > q) stt[m][t][r] = -1e30f;
          }
        }
      }
    }

    // ---- online softmax, in-lane per q-row
    #pragma unroll
    for (int m=0;m<2;++m){
      float vm = stt[m][0][0];
      #pragma unroll
      for (int t=0;t<4;++t)
        #pragma unroll
        for (int r=0;r<4;++r) vm = fmaxf(vm, stt[m][t][r]);
      vm = fmaxf(vm, __shfl_xor(vm, 16, 64));
      vm = fmaxf(vm, __shfl_xor(vm, 32, 64));
      if (!__all(vm <= mrow[m] + 8.f)){       // T13: rescale only on real growth
        float mn = fmaxf(mrow[m], vm);
        float c = __expf(mrow[m]-mn);
        mrow[m]=mn; lrow[m]*=c;
        float cr0 = __shfl(c, rgrp*4+0, 64), cr1 = __shfl(c, rgrp*4+1, 64);
        float cr2 = __shfl(c, rgrp*4+2, 64), cr3 = __shfl(c, rgrp*4+3, 64);
        #pragma unroll
        for (int d=0;d<8;++d){
          oacc[m][d][0]*=cr0; oacc[m][d][1]*=cr1;
          oacc[m][d][2]*=cr2; oacc[m][d][3]*=cr3;
        }
      }
      float lt = 0.f;
      #pragma unroll
      for (int t=0;t<4;++t)
        #pragma unroll
        for (int r=0;r<4;++r){
          float p = __expf(stt[m][t][r]-mrow[m]);
          stt[m][t][r]=p; lt+=p;
        }
      lt += __shfl_xor(lt, 16, 64);
      lt += __shfl_xor(lt, 32, 64);
      lrow[m] += lt;
    }

    // ---- P pack -> per-wave LDS (XOR-swz), 4 consecutive keys per write
    #pragma unroll
    for (int m=0;m<2;++m){
      const int prow = m*16 + cidx;
      char* base = pw + prow*128;
      const int swz = (prow&7)<<4;
      #pragma unroll
      for (int t=0;t<4;++t){
        u16x4 pk = { f2bf(stt[m][t][0]), f2bf(stt[m][t][1]), f2bf(stt[m][t][2]), f2bf(stt[m][t][3]) };
        *(u16x4*)(base + ((t*32 + rgrp*8) ^ swz)) = pk;
      }
    }
    asm volatile("s_waitcnt lgkmcnt(0)" ::: "memory");
    __builtin_amdgcn_sched_barrier(0);

    // ---- O += P V^T
    __builtin_amdgcn_s_setprio(1);
    #pragma unroll
    for (int ks=0; ks<2; ++ks){
      const int swzc = (cidx&7)<<4;
      bf16x8 pa0 = *(const bf16x8*)(pw + (     cidx)*128 + ((ks*64 + rgrp*16) ^ swzc));
      bf16x8 pa1 = *(const bf16x8*)(pw + (16 + cidx)*128 + ((ks*64 + rgrp*16) ^ swzc));
      #pragma unroll
      for (int dsub=0; dsub<8; ++dsub){
        const int d = dsub*16 + cidx;
        const int off = (d*128 + ks*64 + rgrp*16) ^ ((d&7)<<4);
        bf16x8 vf = *(const bf16x8*)(&vl[cur][off]);
        oacc[0][dsub] = mfma16(pa0, vf, oacc[0][dsub]);
        oacc[1][dsub] = mfma16(pa1, vf, oacc[1][dsub]);
      }
    }
    __builtin_amdgcn_s_setprio(0);
    __builtin_amdgcn_s_barrier();             // all reads of buf[cur] done
    cur ^= 1;
  }
  #undef STAGE

  const int b = bh>>4, h = bh&15;
  #pragma unroll
  for (int m=0;m<2;++m){
    float linv = 1.f/lrow[m];
    float ir[4];
    #pragma unroll
    for (int r=0;r<4;++r) ir[r] = __shfl(linv, rgrp*4+r, 64);
    #pragma unroll
    for (int dsub=0;dsub<8;++dsub){
      const int col = h*128 + dsub*16 + cidx;
      #pragma unroll
      for (int r=0;r<4;++r){
        const int srow = qbase + wave*32 + m*16 + rgrp*4 + r;
        Mg[((size_t)b*2048 + srow)*2048 + col] = f2bf(oacc[m][dsub][r]*ir[r]);
      }
    }
  }
}

// ---------------------------------------------------------------- launch
extern "C" void kernel_launch(void* const* d_in, const int* in_sizes, int n_in,
                              void* d_out, int out_size, void* d_ws, size_t ws_size,
                              hipStream_t stream)
{
  (void)in_sizes; (void)n_in; (void)out_size; (void)ws_size;
  const float* x  = (const float*)d_in[0];
  const int*   tp = (const int*)d_in[1];
  const float* Wq = (const float*)d_in[2];
  const float* Wk = (const float*)d_in[3];
  const float* Wv = (const float*)d_in[4];
  const float* Wo = (const float*)d_in[5];

  char* ws = (char*)d_ws;
  bf16_t* xb  = (bf16_t*)(ws);                 // 33.5MB, reused as merged later
  bf16_t* wqb = (bf16_t*)(ws + 33554432);      // wq|wk|wv contiguous = [6144][2048]
  bf16_t* wkb = (bf16_t*)(ws + 41943040);
  bf16_t* wvb = (bf16_t*)(ws + 50331648);
  bf16_t* wob = (bf16_t*)(ws + 58720256);
  bf16_t* vt  = (bf16_t*)(ws + 67108864);      // 33.5MB
  float*  ct  = (float*) (ws + 100663296);     // 512KB
  float*  stb = (float*) (ws + 101187584);     // 512KB  (end ~97MB)
  bf16_t* qr  = (bf16_t*)d_out;                // q_rope in d_out (dead before final GEMM)
  bf16_t* kr  = (bf16_t*)((char*)d_out + 33554432);
  bf16_t* mg  = xb;                            // merged reuses xb

  k_cvt<<<16384,256,0,stream>>>(x,  (u16*)xb);
  k_cvt<<< 4096,256,0,stream>>>(Wq, (u16*)wqb);
  k_cvt<<< 4096,256,0,stream>>>(Wk, (u16*)wkb);
  k_cvt<<< 4096,256,0,stream>>>(Wv, (u16*)wvb);
  k_cvt<<< 4096,256,0,stream>>>(Wo, (u16*)wob);
  k_tab<<<  512,256,0,stream>>>(tp, ct, stb);

  k_gemm<4><<<dim3(48,64),256,0,stream>>>(xb, wqb, qr, kr, vt, ct, stb);
  k_attn<<<1024,256,0,stream>>>(qr, kr, vt, (u16*)mg);
  k_gemm<3><<<dim3(16,64),256,0,stream>>>(mg, wob, d_out, nullptr, nullptr, nullptr, nullptr);
}

// Round 4
// 480.014 us; speedup vs baseline: 1.4421x; 1.0156x over previous
//
#include <hip/hip_runtime.h>
#include <stdint.h>

// ============================================================================
// Fused MHA w/ RoPE, MI355X bf16-MFMA implementation.
// R3: GEMMs rewritten to the 256x256 8-phase template (T2 XOR-swizzle +
// T3/T4 fine phase interleave w/ issue-early staging + T5 setprio + T1 XCD
// swizzle). 512 thr / 8 waves (2Mx4N), BK=64, 128KB dbuf LDS, per-wave
// self-staged half-tiles, vmcnt(0) only at tile boundary. Attn unchanged (R2).
// ============================================================================

using u16 = unsigned short;
typedef __bf16 bf16_t;
typedef __bf16 bf16x8 __attribute__((ext_vector_type(8)));
typedef float  f32x4  __attribute__((ext_vector_type(4)));
typedef u16    u16x4  __attribute__((ext_vector_type(4)));

#define DEVI static __device__ __forceinline__
#define AS1 __attribute__((address_space(1)))
#define AS3 __attribute__((address_space(3)))
#define GLL16(g,l) __builtin_amdgcn_global_load_lds((const AS1 void*)(g), (AS3 void*)(l), 16, 0, 0)

DEVI u16 f2bf(float x){ bf16_t h=(bf16_t)x; return __builtin_bit_cast(u16,h); }
DEVI f32x4 mfma16(bf16x8 a, bf16x8 b, f32x4 c){
  return __builtin_amdgcn_mfma_f32_16x16x32_bf16(a,b,c,0,0,0);
}

// ---------------------------------------------------------------- converts
__global__ __launch_bounds__(256) void k_cvt(const float* __restrict__ in, u16* __restrict__ out){
  int i = blockIdx.x*256 + threadIdx.x;
  float4 v = ((const float4*)in)[i];
  u16x4 o = { f2bf(v.x), f2bf(v.y), f2bf(v.z), f2bf(v.w) };
  ((u16x4*)out)[i] = o;
}

// RoPE table: ct/st [S=2048][64] f32
__global__ __launch_bounds__(256) void k_tab(const int* __restrict__ pos, float* __restrict__ ct, float* __restrict__ stab){
  int i = blockIdx.x*256 + threadIdx.x;      // 0..131071
  int s = i>>6, f = i&63;
  float inv = __expf(-0.14391275442161033f * (float)f);  // 10000^(-f/64)
  float a = (float)pos[s] * inv;
  float sv, cv; sincosf(a, &sv, &cv);
  ct[i] = cv; stab[i] = sv;
}

// ---------------------------------------------------------------- GEMM
// C[M=8192][N] = A[M][K=2048] * Bt[N][K]^T, bf16 in.
// 256x256 tile, BK=64, 8 waves (2Mx4N), per-wave 128x64 out = acc[2][4][4].
// 4 phases/K-tile: (kk,mh) in {(0,0),(0,1),(1,0),(1,1)}; 16 MFMA each.
// LDS [256][64]bf16 per operand, XOR-swz byte^=(row&7)<<4; staged via
// inverse-swizzled global source + linear gload_lds dest (rule 21).
// EPI==4: N=6144 fused QKV (seg0 Q-RoPE, seg1 K-RoPE, seg2 V-transpose).
// EPI==3: N=2048, f32 row-major out.
template<int EPI>
__global__ __launch_bounds__(512,2) void k_gemm(
    const bf16_t* __restrict__ A, const bf16_t* __restrict__ Bt,
    void* __restrict__ O0, void* __restrict__ O1, void* __restrict__ O2,
    const float* __restrict__ ct, const float* __restrict__ stab)
{
  __shared__ char Al[2][32768];
  __shared__ char Bl[2][32768];
  const int tid = threadIdx.x, wave = tid>>6, lane = tid&63;
  const int rgrp = lane>>4, cidx = lane&15;
  const int wm = wave>>2, wn = wave&3;
  constexpr int NB = (EPI==4)? 24 : 8;       // N-blocks; M-blocks = 32
  const int bid = blockIdx.x;
  const int wg = (bid&7)*(4*NB) + (bid>>3);  // bijective XCD swizzle (nwg%8==0)
  const int by = wg & 31, bx = wg >> 5;      // consecutive-in-XCD walk M: B-panel L2-hot
  const int bm = by*256, bn = bx*256;

  const char* Ag = (const char*)A  + (size_t)bm*4096;
  const char* Bg = (const char*)Bt + (size_t)bn*4096;

  const int swz  = (cidx&7)<<4;                          // read-side swizzle
  const int sgsw = ((lane&7)*16) ^ ((lane>>3)<<4);       // staging source swizzle
  const int arow0 = wm*128 + wn*32 + (lane>>3);          // + g*8 (A self-half quarter)
  const int brow0 = (wn>>1)*128 + (wm*2+(wn&1))*32 + (lane>>3);
  const int adst0 = (wm*128 + wn*32)*128;                // LDS byte base (+g*1024)
  const int bdst0 = ((wn>>1)*128 + (wm*2+(wn&1))*32)*128;

  f32x4 acc[2][4][4] = {};
  bf16x8 af[4], bfA[4], bfB[4];

#define STAGE_A(b, kt2) do{ _Pragma("unroll") \
  for (int g=0; g<4; ++g) \
    GLL16(Ag + (size_t)(arow0 + g*8)*4096 + (kt2)*128 + sgsw, &Al[b][adst0 + g*1024]); }while(0)
#define STAGE_B(b, kt2) do{ _Pragma("unroll") \
  for (int g=0; g<4; ++g) \
    GLL16(Bg + (size_t)(brow0 + g*8)*4096 + (kt2)*128 + sgsw, &Bl[b][bdst0 + g*1024]); }while(0)
#define LOAD_AF(MH, KK) do{ _Pragma("unroll") \
  for (int fi=0; fi<4; ++fi) \
    af[fi] = *(const bf16x8*)&Al[cur][(((wm*128 + (MH)*64 + fi*16 + cidx)*128 + (KK)*64 + rgrp*16) ^ swz)]; }while(0)
#define LOAD_BF(DST, KK) do{ _Pragma("unroll") \
  for (int fj=0; fj<4; ++fj) \
    DST[fj] = *(const bf16x8*)&Bl[cur][(((wn*64 + fj*16 + cidx)*128 + (KK)*64 + rgrp*16) ^ swz)]; }while(0)
#define PHASE_TAIL(MH, BFR) do{ \
  __builtin_amdgcn_s_barrier(); \
  asm volatile("s_waitcnt lgkmcnt(0)" ::: "memory"); \
  __builtin_amdgcn_sched_barrier(0); \
  __builtin_amdgcn_s_setprio(1); \
  _Pragma("unroll") for (int fi=0; fi<4; ++fi){ \
    _Pragma("unroll") for (int fj=0; fj<4; ++fj){ \
      acc[MH][fi][fj] = mfma16(af[fi], BFR[fj], acc[MH][fi][fj]); }} \
  __builtin_amdgcn_s_setprio(0); \
  __builtin_amdgcn_sched_barrier(0); \
  __builtin_amdgcn_s_barrier(); }while(0)

  STAGE_A(0, 0); STAGE_B(0, 0);
  asm volatile("s_waitcnt vmcnt(0)" ::: "memory");
  __builtin_amdgcn_s_barrier();
  int cur = 0;
  for (int t=0; t<32; ++t){
    const bool pf = (t < 31);
    // phase 0: kk=0, mh=0  (+ prefetch next A-half)
    if (pf) STAGE_A(cur^1, t+1);
    LOAD_AF(0,0); LOAD_BF(bfA, 0);
    PHASE_TAIL(0, bfA);
    // phase 1: kk=0, mh=1  (+ prefetch next B-half)
    if (pf) STAGE_B(cur^1, t+1);
    LOAD_AF(1,0);
    PHASE_TAIL(1, bfA);
    // phase 2: kk=1, mh=0
    LOAD_AF(0,1); LOAD_BF(bfB, 1);
    PHASE_TAIL(0, bfB);
    // phase 3: kk=1, mh=1
    LOAD_AF(1,1);
    PHASE_TAIL(1, bfB);
    // tile boundary: own prefetch landed; others' guaranteed via barrier
    asm volatile("s_waitcnt vmcnt(0)" ::: "memory");
    __builtin_amdgcn_s_barrier();
    __builtin_amdgcn_sched_barrier(0);
    cur ^= 1;
  }
#undef STAGE_A
#undef STAGE_B
#undef LOAD_AF
#undef LOAD_BF
#undef PHASE_TAIL

  if constexpr (EPI==3){
    float* O = (float*)O0;
    #pragma unroll
    for (int mh=0; mh<2; ++mh)
      #pragma unroll
      for (int fi=0; fi<4; ++fi){
        const int m0 = bm + wm*128 + mh*64 + fi*16 + rgrp*4;
        #pragma unroll
        for (int fj=0; fj<4; ++fj){
          const int n = bn + wn*64 + fj*16 + cidx;
          #pragma unroll
          for (int r=0; r<4; ++r)
            O[(size_t)(m0+r)*2048 + n] = acc[mh][fi][fj][r];
        }
      }
  } else {
    const int seg = bn>>11;                  // block-uniform: 0=Q, 1=K, 2=V
    if (seg==2){
      u16* O = (u16*)O2;                     // v_t [bh][128][2048]
      #pragma unroll
      for (int mh=0; mh<2; ++mh)
        #pragma unroll
        for (int fi=0; fi<4; ++fi){
          const int m0 = bm + wm*128 + mh*64 + fi*16 + rgrp*4;
          const int b = m0>>11, s0 = m0&2047;
          #pragma unroll
          for (int fj=0; fj<4; ++fj){
            const int nl = (bn + wn*64 + fj*16 + cidx) & 2047;
            const int h = nl>>7, d = nl&127;
            u16x4 pk = { f2bf(acc[mh][fi][fj][0]), f2bf(acc[mh][fi][fj][1]),
                         f2bf(acc[mh][fi][fj][2]), f2bf(acc[mh][fi][fj][3]) };
            *(u16x4*)(O + ((size_t)((b*16+h)*128 + d)*2048 + s0)) = pk;
          }
        }
    } else {
      u16* O = seg ? (u16*)O1 : (u16*)O0;    // [bh][2048][128]
      const float qs = seg ? 1.0f : 0.08838834764831845f;  // 1/sqrt(128) on Q
      #pragma unroll
      for (int fj=0; fj<4; ++fj){
        const int nl = (bn + wn*64 + fj*16 + cidx) & 2047;
        const int h = nl>>7, d = nl&127, f = (nl&127)>>1;
        #pragma unroll
        for (int mh=0; mh<2; ++mh)
          #pragma unroll
          for (int fi=0; fi<4; ++fi){
            #pragma unroll
            for (int r=0; r<4; ++r){
              const int m = bm + wm*128 + mh*64 + fi*16 + rgrp*4 + r;
              const int b = m>>11, s = m&2047;
              float v = acc[mh][fi][fj][r];
              float p = __shfl_xor(v, 1, 64);  // RoPE partner: d^1 lives in lane^1
              float cv = ct[s*64+f], sv = stab[s*64+f];
              float o = (d&1) ? (p*sv + v*cv) : (v*cv - p*sv);
              o *= qs;
              O[(size_t)(b*16+h)*262144 + (size_t)s*128 + d] = f2bf(o);
            }
          }
      }
    }
  }
}

// ---------------------------------------------------------------- flash attn
// 1-D grid, 1024 blocks, LPT order: qt = 15 - bid/64, bh = bid%64.
// QBLK=128: wave w owns q rows [qt*128 + w*32, +32) = 2 M-fragments.
// Swapped QK^T: stt[m][t] = mfma(K_frag, Q_frag) -> S[key][q], q = lane&15.
// Softmax: in-lane 16-value reduce + shfl_xor(16,32). P packed as u16x4 ->
// 8 ds_write_b64/wave. K/V double-buffered, XOR-swizzled (rule 21), counted
// vmcnt(8) + raw s_barrier (T3/T4), setprio (T5), defer-max (T13).
__global__ __launch_bounds__(256,2) void k_attn(
  const bf16_t* __restrict__ Q, const bf16_t* __restrict__ K,
  const bf16_t* __restrict__ Vt, u16* __restrict__ Mg)
{
  __shared__ char kl[2][16384];
  __shared__ char vl[2][16384];
  __shared__ char pl[4][4096];                // per-wave P: 32 q-rows x 128B, XOR-swz
  const int tid=threadIdx.x, wave=tid>>6, lane=tid&63;
  const int rgrp=lane>>4, cidx=lane&15;
  const int bid=blockIdx.x;
  const int qt = 15 - (bid>>6);
  const int bh = bid & 63;
  const int qbase = qt*128;
  const int last = 2*qt + 1;                  // inclusive last k-tile

  bf16x8 qf[2][4];                            // B-operand: lane <- q row m*16+cidx
  #pragma unroll
  for (int m=0;m<2;++m){
    const bf16_t* qp = Q + ((size_t)bh*2048 + qbase + wave*32 + m*16 + cidx)*128 + rgrp*8;
    #pragma unroll
    for (int ds=0; ds<4; ++ds) qf[m][ds] = *(const bf16x8*)(qp + ds*32);
  }
  f32x4 oacc[2][8] = {};
  float mrow[2] = {-1e30f,-1e30f};
  float lrow[2] = {0.f,0.f};

  const char* Kg = (const char*)K  + (size_t)bh*524288;
  const char* Vg = (const char*)Vt + (size_t)bh*524288;
  char* pw = pl[wave];
  const int L0 = tid*16;
  const int qrow0 = qbase + wave*32 + cidx;   // q-row of frag m: qrow0 + m*16

  #define STAGE(buf, kt_) do{                                                  \
    _Pragma("unroll")                                                          \
    for (int i_=0;i_<4;++i_){                                                  \
      int L_ = i_*4096 + L0;                                                   \
      int row_ = L_>>8;                                                        \
      int in_ = (L_&255) ^ ((row_&7)<<4);                                      \
      GLL16(Kg + (size_t)((kt_)*64+row_)*256 + in_, &kl[buf][i_*4096 + wave*1024]); \
    }                                                                          \
    _Pragma("unroll")                                                          \
    for (int i_=0;i_<4;++i_){                                                  \
      int L_ = i_*4096 + L0;                                                   \
      int d_ = L_>>7;                                                          \
      int in_ = (L_&127) ^ ((d_&7)<<4);                                        \
      GLL16(Vg + (size_t)d_*4096 + (kt_)*128 + in_, &vl[buf][i_*4096 + wave*1024]); \
    }                                                                          \
  }while(0)

  STAGE(0, 0);
  int cur = 0;
  for (int kt=0; kt<=last; ++kt){
    const bool pf = (kt < last);
    if (pf) STAGE(cur^1, kt+1);               // 8 more GLLs in flight
    if (pf) asm volatile("s_waitcnt vmcnt(8)" ::: "memory");
    else    asm volatile("s_waitcnt vmcnt(0)" ::: "memory");
    __builtin_amdgcn_s_barrier();             // buf[cur] ready everywhere

    // ---- S^T = K Q^T : stt[m][t][r] = S[key = kt*64+t*16+rgrp*4+r][q = qrow0+m*16]
    f32x4 stt[2][4];
    #pragma unroll
    for (int m=0;m<2;++m)
      #pragma unroll
      for (int t=0;t<4;++t) stt[m][t] = (f32x4){0.f,0.f,0.f,0.f};
    __builtin_amdgcn_s_setprio(1);
    #pragma unroll
    for (int t=0;t<4;++t){
      const int krow = t*16 + cidx;           // A-operand: lane <- K row krow
      #pragma unroll
      for (int ds=0; ds<4; ++ds){
        const int off = (krow*256 + ds*64 + rgrp*16) ^ ((krow&7)<<4);
        bf16x8 kf = *(const bf16x8*)(&kl[cur][off]);
        stt[0][t] = mfma16(kf, qf[0][ds], stt[0][t]);
        stt[1][t] = mfma16(kf, qf[1][ds], stt[1][t]);
      }
    }
    __builtin_amdgcn_s_setprio(0);

    // ---- causal mask (only the last two tiles of this q-block can clip)
    if (kt >= 2*qt){
      #pragma unroll
      for (int m=0;m<2;++m){
        const int q = qrow0 + m*16;
        #pragma unroll
        for (int t=0;t<4;++t){
          #pragma unroll
          for (int r=0;r<4;++r){
            const int key = kt*64 + t*16 + rgrp*4 + r;
            if (key > q) stt[m][t][r] = -1e30f;
          }
        }
      }
    }

    // ---- online softmax, in-lane per q-row
    #pragma unroll
    for (int m=0;m<2;++m){
      float vm = stt[m][0][0];
      #pragma unroll
      for (int t=0;t<4;++t)
        #pragma unroll
        for (int r=0;r<4;++r) vm = fmaxf(vm, stt[m][t][r]);
      vm = fmaxf(vm, __shfl_xor(vm, 16, 64));
      vm = fmaxf(vm, __shfl_xor(vm, 32, 64));
      if (!__all(vm <= mrow[m] + 8.f)){       // T13: rescale only on real growth
        float mn = fmaxf(mrow[m], vm);
        float c = __expf(mrow[m]-mn);
        mrow[m]=mn; lrow[m]*=c;
        float cr0 = __shfl(c, rgrp*4+0, 64), cr1 = __shfl(c, rgrp*4+1, 64);
        float cr2 = __shfl(c, rgrp*4+2, 64), cr3 = __shfl(c, rgrp*4+3, 64);
        #pragma unroll
        for (int d=0;d<8;++d){
          oacc[m][d][0]*=cr0; oacc[m][d][1]*=cr1;
          oacc[m][d][2]*=cr2; oacc[m][d][3]*=cr3;
        }
      }
      float lt = 0.f;
      #pragma unroll
      for (int t=0;t<4;++t)
        #pragma unroll
        for (int r=0;r<4;++r){
          float p = __expf(stt[m][t][r]-mrow[m]);
          stt[m][t][r]=p; lt+=p;
        }
      lt += __shfl_xor(lt, 16, 64);
      lt += __shfl_xor(lt, 32, 64);
      lrow[m] += lt;
    }

    // ---- P pack -> per-wave LDS (XOR-swz), 4 consecutive keys per write
    #pragma unroll
    for (int m=0;m<2;++m){
      const int prow = m*16 + cidx;
      char* base = pw + prow*128;
      const int swz = (prow&7)<<4;
      #pragma unroll
      for (int t=0;t<4;++t){
        u16x4 pk = { f2bf(stt[m][t][0]), f2bf(stt[m][t][1]), f2bf(stt[m][t][2]), f2bf(stt[m][t][3]) };
        *(u16x4*)(base + ((t*32 + rgrp*8) ^ swz)) = pk;
      }
    }
    asm volatile("s_waitcnt lgkmcnt(0)" ::: "memory");
    __builtin_amdgcn_sched_barrier(0);

    // ---- O += P V^T
    __builtin_amdgcn_s_setprio(1);
    #pragma unroll
    for (int ks=0; ks<2; ++ks){
      const int swzc = (cidx&7)<<4;
      bf16x8 pa0 = *(const bf16x8*)(pw + (     cidx)*128 + ((ks*64 + rgrp*16) ^ swzc));
      bf16x8 pa1 = *(const bf16x8*)(pw + (16 + cidx)*128 + ((ks*64 + rgrp*16) ^ swzc));
      #pragma unroll
      for (int dsub=0; dsub<8; ++dsub){
        const int d = dsub*16 + cidx;
        const int off = (d*128 + ks*64 + rgrp*16) ^ ((d&7)<<4);
        bf16x8 vf = *(const bf16x8*)(&vl[cur][off]);
        oacc[0][dsub] = mfma16(pa0, vf, oacc[0][dsub]);
        oacc[1][dsub] = mfma16(pa1, vf, oacc[1][dsub]);
      }
    }
    __builtin_amdgcn_s_setprio(0);
    __builtin_amdgcn_s_barrier();             // all reads of buf[cur] done
    cur ^= 1;
  }
  #undef STAGE

  const int b = bh>>4, h = bh&15;
  #pragma unroll
  for (int m=0;m<2;++m){
    float linv = 1.f/lrow[m];
    float ir[4];
    #pragma unroll
    for (int r=0;r<4;++r) ir[r] = __shfl(linv, rgrp*4+r, 64);
    #pragma unroll
    for (int dsub=0;dsub<8;++dsub){
      const int col = h*128 + dsub*16 + cidx;
      #pragma unroll
      for (int r=0;r<4;++r){
        const int srow = qbase + wave*32 + m*16 + rgrp*4 + r;
        Mg[((size_t)b*2048 + srow)*2048 + col] = f2bf(oacc[m][dsub][r]*ir[r]);
      }
    }
  }
}

// ---------------------------------------------------------------- launch
extern "C" void kernel_launch(void* const* d_in, const int* in_sizes, int n_in,
                              void* d_out, int out_size, void* d_ws, size_t ws_size,
                              hipStream_t stream)
{
  (void)in_sizes; (void)n_in; (void)out_size; (void)ws_size;
  const float* x  = (const float*)d_in[0];
  const int*   tp = (const int*)d_in[1];
  const float* Wq = (const float*)d_in[2];
  const float* Wk = (const float*)d_in[3];
  const float* Wv = (const float*)d_in[4];
  const float* Wo = (const float*)d_in[5];

  char* ws = (char*)d_ws;
  bf16_t* xb  = (bf16_t*)(ws);                 // 33.5MB, reused as merged later
  bf16_t* wqb = (bf16_t*)(ws + 33554432);      // wq|wk|wv contiguous = [6144][2048]
  bf16_t* wkb = (bf16_t*)(ws + 41943040);
  bf16_t* wvb = (bf16_t*)(ws + 50331648);
  bf16_t* wob = (bf16_t*)(ws + 58720256);
  bf16_t* vt  = (bf16_t*)(ws + 67108864);      // 33.5MB
  float*  ct  = (float*) (ws + 100663296);     // 512KB
  float*  stb = (float*) (ws + 101187584);     // 512KB  (end ~97MB)
  bf16_t* qr  = (bf16_t*)d_out;                // q_rope in d_out (dead before final GEMM)
  bf16_t* kr  = (bf16_t*)((char*)d_out + 33554432);
  bf16_t* mg  = xb;                            // merged reuses xb

  k_cvt<<<16384,256,0,stream>>>(x,  (u16*)xb);
  k_cvt<<< 4096,256,0,stream>>>(Wq, (u16*)wqb);
  k_cvt<<< 4096,256,0,stream>>>(Wk, (u16*)wkb);
  k_cvt<<< 4096,256,0,stream>>>(Wv, (u16*)wvb);
  k_cvt<<< 4096,256,0,stream>>>(Wo, (u16*)wob);
  k_tab<<<  512,256,0,stream>>>(tp, ct, stb);

  k_gemm<4><<<768,512,0,stream>>>(xb, wqb, qr, kr, vt, ct, stb);
  k_attn<<<1024,256,0,stream>>>(qr, kr, vt, (u16*)mg);
  k_gemm<3><<<256,512,0,stream>>>(mg, wob, d_out, nullptr, nullptr, nullptr, nullptr);
}